// Round 7
// baseline (430.930 us; speedup 1.0000x reference)
//
#include <hip/hip_runtime.h>
#include <math.h>

// ---------------------------------------------------------------------------
// TemporalGuidedModule round 7 (base = r4, 195us):
//  - gemm2_k staging COALESCING FIX: lane=(row=tid>>3, seg=tid&7) -> each 8
//    lanes read one full 128B line (was 32 rows strided 512B per instr).
//    Same remap for W staging and all epilogue copy-outs; OMODE1 (cm f32)
//    now bounces through a transposed [64][132] f32 LDS tile for dense lines.
//  - msda: r4 body + __launch_bounds__(256,4) (VGPR 140 -> <=128, +1 occ band).
// ---------------------------------------------------------------------------

#define PIX 16384
#define BATCH 2
#define CH 256

typedef short bf16x8 __attribute__((ext_vector_type(8)));
typedef float f32x4 __attribute__((ext_vector_type(4)));

__device__ __forceinline__ ushort f2bf(float f) {
  union { float f; unsigned u; } v; v.f = f;
  unsigned u = v.u;
  unsigned r = u + 0x7fffu + ((u >> 16) & 1u);   // RNE
  return (ushort)(r >> 16);
}
__device__ __forceinline__ float bfl(unsigned u) {
  union { unsigned u; float f; } v; v.u = u << 16; return v.f;
}
__device__ __forceinline__ float bfh(unsigned u) {
  union { unsigned u; float f; } v; v.u = u & 0xffff0000u; return v.f;
}
__device__ __forceinline__ unsigned fuse_u32(unsigned a, unsigned b, bool mul) {
  float rl = mul ? bfl(a) * bfl(b) : bfl(a) + bfl(b);
  float rh = mul ? bfh(a) * bfh(b) : bfh(a) + bfh(b);
  return (unsigned)f2bf(rl) | ((unsigned)f2bf(rh) << 16);
}

// --------------------------------------------------------------------------
// Weight prep + bias concat.
// --------------------------------------------------------------------------
__global__ __launch_bounds__(256) void wprep_k(
    const float* __restrict__ W_in1, const float* __restrict__ Wo,
    const float* __restrict__ Wt1, const float* __restrict__ Wt2,
    const float* __restrict__ Wout, const float* __restrict__ Ws,
    const float* __restrict__ Wa, const float* __restrict__ bs_off,
    const float* __restrict__ ba, ushort* __restrict__ wb,
    float* __restrict__ bsa)
{
  const int blk = blockIdx.x, k = threadIdx.x;
  if (blk >= 1472) {
    if (k < 128) bsa[k] = bs_off[k];
    else if (k < 192) bsa[k] = ba[k - 128];
    return;
  }
  const float* src;
  if (blk < 256) src = W_in1 + (size_t)blk * 256;
  else if (blk < 512) src = Wo + (size_t)(blk - 256) * 256;
  else if (blk < 768) src = Wt1 + (size_t)(blk - 512) * 256;
  else if (blk < 1024) src = Wt2 + (size_t)(blk - 768) * 256;
  else if (blk < 1280) src = Wout + (size_t)(blk - 1024) * 256;
  else if (blk < 1408) src = Ws + (size_t)(blk - 1280) * 256;
  else src = Wa + (size_t)(blk - 1408) * 256;
  wb[(size_t)blk * 256 + k] = f2bf(src[k]);
}

// Wv' = Wv @ W_in2 (bf16), bv' = Wv @ b_in2 + bv.
__global__ __launch_bounds__(256) void wvcomp_k(
    const float* __restrict__ Wv, const float* __restrict__ W_in2,
    const float* __restrict__ b_in2, const float* __restrict__ bv,
    ushort* __restrict__ Wvp, float* __restrict__ bvp)
{
  const int o = blockIdx.x, k = threadIdx.x;
  float acc = 0.f;
  #pragma unroll 8
  for (int c = 0; c < 256; ++c)
    acc += Wv[(size_t)o * 256 + c] * W_in2[(size_t)c * 256 + k];
  Wvp[(size_t)o * 256 + k] = f2bf(acc);
  __shared__ float red[256];
  red[k] = Wv[(size_t)o * 256 + k] * b_in2[k];
  __syncthreads();
  for (int s = 128; s > 0; s >>= 1) {
    if (k < s) red[k] += red[k + s];
    __syncthreads();
  }
  if (k == 0) bvp[o] = red[0] + bv[o];
}

// --------------------------------------------------------------------------
// Transpose-convert: [B][C][P] f32 -> [B][P][C] bf16.
// --------------------------------------------------------------------------
__global__ __launch_bounds__(256) void tconv_k(const float* __restrict__ in,
                                               ushort* __restrict__ out)
{
  __shared__ float t[32][33];
  const int tid = threadIdx.x;
  const int b = blockIdx.z;
  const int p0 = blockIdx.x * 32, c0 = blockIdx.y * 32;
  const int tx = tid & 31, ty = tid >> 5;
  const float* inb = in + (size_t)b * CH * PIX;
  #pragma unroll
  for (int i = 0; i < 4; ++i)
    t[ty + i * 8][tx] = inb[(size_t)(c0 + ty + i * 8) * PIX + p0 + tx];
  __syncthreads();
  const int cx = (tid & 15) * 2, py = tid >> 4;
  ushort* outb = out + (size_t)b * PIX * CH;
  #pragma unroll
  for (int i = 0; i < 2; ++i) {
    int pl = py + i * 16;
    unsigned lo = f2bf(t[cx][pl]);
    unsigned hi = f2bf(t[cx + 1][pl]);
    *(unsigned*)(outb + (size_t)(p0 + pl) * CH + c0 + cx) = lo | (hi << 16);
  }
}

// --------------------------------------------------------------------------
// MFMA GEMM: Out[p][o] = sum_k X[p][k]*W[o][k] + bias[o]
// Tile 128p x 64o, BK=64, 256 thr (4 waves, wave = 32p x 64o = 2x4 frags).
// Double-buffered swizzled LDS; single barrier per K-step.
// Staging (coalesced): lane = (row = tid>>3 [+32/round], 16B seg = tid&7);
//   8 lanes read one full 128B line. LDS slot = seg ^ (row&7) (XOR swizzle).
// OMODE 0: pm bf16 out; 1: cm f32 out (transposed bounce); 2: pm f32 out.
// FUSE 0: none; 1: x*=in2; 2: x+=in2 (in2 pm bf16).
// --------------------------------------------------------------------------
template<int FUSE, bool RELU, int OMODE>
__global__ __launch_bounds__(256, 3) void gemm2_k(
    const ushort* __restrict__ in, const ushort* __restrict__ in2,
    const ushort* __restrict__ Wb, const float* __restrict__ bias,
    void* __restrict__ out, int ldo, size_t obstride)
{
  __shared__ __align__(16) char smem[49152];
  const int tid = threadIdx.x;
  const int b = blockIdx.z;
  const int p0 = blockIdx.x * 128;
  const int o0 = blockIdx.y * 64;

  const ushort* inb = in + (size_t)b * PIX * CH;

  const int srow = tid >> 3, sseg = tid & 7;   // staging row-group + 16B seg
  const int ssw = (srow & 7);                  // row&7 invariant across rounds (+32)
  const ushort* xsrc = inb + (size_t)(p0 + srow) * CH + sseg * 8;
  const ushort* x2src = (FUSE != 0)
      ? in2 + (size_t)b * PIX * CH + (size_t)(p0 + srow) * CH + sseg * 8
      : (const ushort*)nullptr;
  const ushort* wsrc = Wb + (size_t)(o0 + srow) * CH + sseg * 8;

  const int l = tid & 63, wv = tid >> 6;
  const int lr = l & 15, g4 = l >> 4;

  f32x4 acc[2][4];
  #pragma unroll
  for (int i = 0; i < 2; ++i)
    #pragma unroll
    for (int j = 0; j < 4; ++j) acc[i][j] = (f32x4){0.f, 0.f, 0.f, 0.f};

  uint4 xr[4], x2r[4], wr[2];

#define LOADT(kb)                                                              \
  {                                                                            \
    _Pragma("unroll")                                                          \
    for (int r = 0; r < 4; ++r)                                                \
      xr[r] = *(const uint4*)(xsrc + (kb) + (size_t)r * 32 * CH);              \
    if (FUSE != 0) {                                                           \
      _Pragma("unroll")                                                        \
      for (int r = 0; r < 4; ++r)                                              \
        x2r[r] = *(const uint4*)(x2src + (kb) + (size_t)r * 32 * CH);          \
    }                                                                          \
    _Pragma("unroll")                                                          \
    for (int r = 0; r < 2; ++r)                                                \
      wr[r] = *(const uint4*)(wsrc + (kb) + (size_t)r * 32 * CH);              \
  }

#define WRITET(buf)                                                            \
  {                                                                            \
    _Pragma("unroll")                                                          \
    for (int r = 0; r < 4; ++r) {                                              \
      uint4 v = xr[r];                                                         \
      if (FUSE != 0) {                                                         \
        unsigned* pa = (unsigned*)&v;                                          \
        const unsigned* pb = (const unsigned*)&x2r[r];                         \
        _Pragma("unroll")                                                      \
        for (int w = 0; w < 4; ++w) pa[w] = fuse_u32(pa[w], pb[w], FUSE == 1); \
      }                                                                        \
      *(uint4*)(smem + (buf) * 16384 + (srow + r * 32) * 128 +                 \
                ((sseg ^ ssw) * 16)) = v;                                      \
    }                                                                          \
    _Pragma("unroll")                                                          \
    for (int r = 0; r < 2; ++r)                                                \
      *(uint4*)(smem + 32768 + (buf) * 8192 + (srow + r * 32) * 128 +          \
                ((sseg ^ ssw) * 16)) = wr[r];                                  \
  }

  LOADT(0)
  WRITET(0)
  __syncthreads();

  for (int t = 0; t < 4; ++t) {
    if (t < 3) LOADT((t + 1) * 64)
    const char* XB = smem + (t & 1) * 16384;
    const char* WB = smem + 32768 + (t & 1) * 8192;
    bf16x8 af[2][2], bfr[4][2];
    #pragma unroll
    for (int fm = 0; fm < 2; ++fm) {
      const int p = wv * 32 + fm * 16 + lr;
      #pragma unroll
      for (int kh = 0; kh < 2; ++kh)
        af[fm][kh] = *(const bf16x8*)(XB + p * 128 + (((kh * 4 + g4) ^ (p & 7)) * 16));
    }
    #pragma unroll
    for (int fn = 0; fn < 4; ++fn) {
      const int o = fn * 16 + lr;
      #pragma unroll
      for (int kh = 0; kh < 2; ++kh)
        bfr[fn][kh] = *(const bf16x8*)(WB + o * 128 + (((kh * 4 + g4) ^ (o & 7)) * 16));
    }
    #pragma unroll
    for (int fm = 0; fm < 2; ++fm)
      #pragma unroll
      for (int fn = 0; fn < 4; ++fn) {
        acc[fm][fn] = __builtin_amdgcn_mfma_f32_16x16x32_bf16(af[fm][0], bfr[fn][0], acc[fm][fn], 0, 0, 0);
        acc[fm][fn] = __builtin_amdgcn_mfma_f32_16x16x32_bf16(af[fm][1], bfr[fn][1], acc[fm][fn], 0, 0, 0);
      }
    if (t < 3) WRITET((t + 1) & 1)
    __syncthreads();
  }
#undef LOADT
#undef WRITET

  // ---- epilogue ---- C/D: col(o) = lr, row(p) = g4*4 + reg
  float bvv[4];
  #pragma unroll
  for (int fn = 0; fn < 4; ++fn) bvv[fn] = bias[o0 + fn * 16 + lr];

  if (OMODE == 1) {               // cm f32 via TRANSPOSED bounce El2[64][132] f32
    float* El2 = (float*)smem;
    #pragma unroll
    for (int fm = 0; fm < 2; ++fm)
      #pragma unroll
      for (int fn = 0; fn < 4; ++fn) {
        float4 v;
        v.x = acc[fm][fn][0] + bvv[fn]; v.y = acc[fm][fn][1] + bvv[fn];
        v.z = acc[fm][fn][2] + bvv[fn]; v.w = acc[fm][fn][3] + bvv[fn];
        if (RELU) {
          v.x = fmaxf(v.x, 0.f); v.y = fmaxf(v.y, 0.f);
          v.z = fmaxf(v.z, 0.f); v.w = fmaxf(v.w, 0.f);
        }
        *(float4*)&El2[(size_t)(fn * 16 + lr) * 132 + wv * 32 + fm * 16 + g4 * 4] = v;
      }
    __syncthreads();
    float* outb = (float*)out + (size_t)b * obstride;
    const int og = tid >> 5, seg = tid & 31;
    #pragma unroll
    for (int r = 0; r < 8; ++r) {
      const int orow = og + r * 8;
      float4 v = *(float4*)(smem + orow * 528 + seg * 16);
      *(float4*)(outb + (size_t)(o0 + orow) * ldo + p0 + seg * 4) = v;
    }
  } else if (OMODE == 0) {        // pm bf16 via LDS bounce [128][72] halves
    ushort* El = (ushort*)smem;
    #pragma unroll
    for (int fm = 0; fm < 2; ++fm)
      #pragma unroll
      for (int fn = 0; fn < 4; ++fn)
        #pragma unroll
        for (int r = 0; r < 4; ++r) {
          const int p = wv * 32 + fm * 16 + g4 * 4 + r;
          float v = acc[fm][fn][r] + bvv[fn];
          if (RELU) v = fmaxf(v, 0.f);
          El[p * 72 + fn * 16 + lr] = f2bf(v);
        }
    __syncthreads();
    ushort* outb = (ushort*)out + (size_t)b * obstride;
    const int rg = tid >> 3, seg = tid & 7;
    #pragma unroll
    for (int r = 0; r < 4; ++r) {
      const int row = rg + r * 32;
      uint4 v = *(uint4*)(smem + row * 144 + seg * 16);
      *(uint4*)(outb + (size_t)(p0 + row) * ldo + o0 + seg * 8) = v;
    }
  } else {                        // OMODE 2: pm f32 via LDS bounce [128][68] f32
    float* El = (float*)smem;
    #pragma unroll
    for (int fm = 0; fm < 2; ++fm)
      #pragma unroll
      for (int fn = 0; fn < 4; ++fn)
        #pragma unroll
        for (int r = 0; r < 4; ++r) {
          const int p = wv * 32 + fm * 16 + g4 * 4 + r;
          float v = acc[fm][fn][r] + bvv[fn];
          if (RELU) v = fmaxf(v, 0.f);
          El[p * 68 + fn * 16 + lr] = v;
        }
    __syncthreads();
    float* outb = (float*)out + (size_t)b * obstride;
    const int rg = tid >> 4, seg = tid & 15;
    #pragma unroll
    for (int r = 0; r < 8; ++r) {
      const int row = rg + r * 16;
      float4 v = *(float4*)(smem + row * 272 + seg * 16);
      *(float4*)(outb + (size_t)(p0 + row) * ldo + o0 + seg * 4) = v;
    }
  }
}

// --------------------------------------------------------------------------
// Fused MSDA (r4 body): thread per (pixel, head, 16-dim half), full unroll.
// launch_bounds(256,4) caps VGPR at 128 (was 140) for +1 occupancy band.
// value pm bf16 [B][P][256]; sa sample-major f32 [B][P][192]; out pm bf16.
// --------------------------------------------------------------------------
__global__ __launch_bounds__(256, 4) void msda_k(
    const ushort* __restrict__ value, const float* __restrict__ sa,
    ushort* __restrict__ out)
{
  const int t = blockIdx.x * 256 + threadIdx.x;   // B*P*16
  const int dh = t & 1;
  const int h = (t >> 1) & 7;
  const int pg = t >> 4;
  const int b = pg >> 14;
  const int p = pg & (PIX - 1);
  const int px = p & 127, py = p >> 7;

  const ushort* vb = value + (size_t)b * PIX * CH;
  const float* sp = sa + (size_t)pg * 192;

  float4 la = *(const float4*)(sp + 128 + h * 8);
  float4 lb = *(const float4*)(sp + 128 + h * 8 + 4);
  float lg[8] = {la.x, la.y, la.z, la.w, lb.x, lb.y, lb.z, lb.w};
  float m = lg[0];
  #pragma unroll
  for (int i = 1; i < 8; ++i) m = fmaxf(m, lg[i]);
  float s = 0.f;
  #pragma unroll
  for (int i = 0; i < 8; ++i) { lg[i] = __expf(lg[i] - m); s += lg[i]; }
  const float inv = 1.f / s;

  float of[16];
  #pragma unroll
  for (int j = 0; j < 4; ++j)
    *(float4*)&of[j * 4] = *(const float4*)(sp + h * 16 + j * 4);

  float acc[16];
  #pragma unroll
  for (int i = 0; i < 16; ++i) acc[i] = 0.f;

  #pragma unroll
  for (int pt = 0; pt < 8; ++pt) {
    const float ox = of[2 * pt], oy = of[2 * pt + 1];
    const float aw = lg[pt] * inv;
    const float ix = px + ox, iy = py + oy;   // grid_sample -0.5 cancels
    const float xf = floorf(ix), yf = floorf(iy);
    const float fx = ix - xf, fy = iy - yf;
    const int x0 = (int)xf, y0 = (int)yf;
    #pragma unroll
    for (int cr = 0; cr < 4; ++cr) {
      const int dx = cr & 1, dy = cr >> 1;
      const int xx = x0 + dx, yy = y0 + dy;
      const float wx = dx ? fx : (1.f - fx);
      const float wy = dy ? fy : (1.f - fy);
      const bool valid = ((unsigned)xx < 128u) & ((unsigned)yy < 128u);
      float w = valid ? (wx * wy * aw) : 0.f;
      const int xc = min(max(xx, 0), 127), yc = min(max(yy, 0), 127);
      const ushort* vr = vb + ((size_t)(yc * 128 + xc) * CH + h * 32 + dh * 16);
      uint4 q0 = *(const uint4*)vr;
      uint4 q1 = *(const uint4*)(vr + 8);
      const unsigned* qw0 = (const unsigned*)&q0;
      const unsigned* qw1 = (const unsigned*)&q1;
      #pragma unroll
      for (int ww = 0; ww < 4; ++ww) {
        acc[2 * ww + 0] = fmaf(w, bfl(qw0[ww]), acc[2 * ww + 0]);
        acc[2 * ww + 1] = fmaf(w, bfh(qw0[ww]), acc[2 * ww + 1]);
        acc[8 + 2 * ww + 0] = fmaf(w, bfl(qw1[ww]), acc[8 + 2 * ww + 0]);
        acc[8 + 2 * ww + 1] = fmaf(w, bfh(qw1[ww]), acc[8 + 2 * ww + 1]);
      }
    }
  }
  unsigned r[8];
  #pragma unroll
  for (int k = 0; k < 8; ++k)
    r[k] = (unsigned)f2bf(acc[2 * k]) | ((unsigned)f2bf(acc[2 * k + 1]) << 16);
  ushort* dst = out + (size_t)pg * CH + h * 32 + dh * 16;
  *(uint4*)dst = *(uint4*)&r[0];
  *(uint4*)(dst + 8) = *(uint4*)&r[4];
}

extern "C" void kernel_launch(void* const* d_in, const int* in_sizes, int n_in,
                              void* d_out, int out_size, void* d_ws, size_t ws_size,
                              hipStream_t stream)
{
  const float* xt     = (const float*)d_in[0];
  const float* xt_1   = (const float*)d_in[1];
  const float* W_in1  = (const float*)d_in[2];
  const float* b_in1  = (const float*)d_in[3];
  const float* W_in2  = (const float*)d_in[4];
  const float* b_in2  = (const float*)d_in[5];
  const float* Wv     = (const float*)d_in[6];
  const float* bv     = (const float*)d_in[7];
  const float* Ws     = (const float*)d_in[8];
  const float* bs_off = (const float*)d_in[9];
  const float* Wa     = (const float*)d_in[10];
  const float* ba     = (const float*)d_in[11];
  const float* Wo     = (const float*)d_in[12];
  const float* bo     = (const float*)d_in[13];
  const float* Wt1    = (const float*)d_in[14];
  const float* bt1    = (const float*)d_in[15];
  const float* Wt2    = (const float*)d_in[16];
  const float* bt2    = (const float*)d_in[17];
  const float* Wout   = (const float*)d_in[18];
  const float* bout   = (const float*)d_in[19];

  char* ws = (char*)d_ws;
  const size_t SLOT = (size_t)BATCH * PIX * CH * 2;          // 16.78 MB
  const size_t SAB  = (size_t)BATCH * PIX * 192 * 4;         // 25.17 MB
  ushort* s0 = (ushort*)(ws + 0 * SLOT);   // xt_pm  -> xt_star
  ushort* s1 = (ushort*)(ws + 1 * SLOT);   // xt1_pm -> h1
  ushort* s2 = (ushort*)(ws + 2 * SLOT);   // x1 (live to end)
  ushort* s3 = (ushort*)(ws + 3 * SLOT);   // value  -> tg
  ushort* s4 = (ushort*)(ws + 4 * SLOT);   // msda_out
  float*  sa = (float*)(ws + 5 * SLOT);    // [B][P][192] offs+attn
  char* wbase = ws + 5 * SLOT + SAB;
  ushort* wb  = (ushort*)wbase;            // 1472x256 bf16
  ushort* wvp = (ushort*)(wbase + (size_t)1472 * 256 * 2);   // 256x256 bf16
  float* bsa  = (float*)(wbase + (size_t)1472 * 256 * 2 + (size_t)256 * 256 * 2);
  float* bvp  = bsa + 192;

  ushort* wb_in1 = wb;
  ushort* wb_o   = wb + 65536;
  ushort* wb_t1  = wb + 131072;
  ushort* wb_t2  = wb + 196608;
  ushort* wb_out = wb + 262144;
  ushort* wb_sa  = wb + 327680;            // 192 rows: Ws then Wa

  dim3 blk(256);
  dim3 gT(PIX / 32, CH / 32, BATCH);
  dim3 gF(PIX / 128, 4, BATCH);            // Cout=256
  dim3 gS(PIX / 128, 3, BATCH);            // Cout=192
  const size_t OBS = (size_t)PIX * CH;     // pm bf16 batch stride (elems)

  wprep_k<<<1473, blk, 0, stream>>>(W_in1, Wo, Wt1, Wt2, Wout, Ws, Wa, bs_off, ba, wb, bsa);
  wvcomp_k<<<256, blk, 0, stream>>>(Wv, W_in2, b_in2, bv, wvp, bvp);
  tconv_k<<<gT, blk, 0, stream>>>(xt, s0);
  tconv_k<<<gT, blk, 0, stream>>>(xt_1, s1);

  gemm2_k<0, false, 0><<<gF, blk, 0, stream>>>(s0, nullptr, wb_in1, b_in1, s2, CH, OBS);          // x1
  gemm2_k<0, false, 0><<<gF, blk, 0, stream>>>(s1, nullptr, wvp, bvp, s3, CH, OBS);               // value
  gemm2_k<0, false, 2><<<gS, blk, 0, stream>>>(s2, nullptr, wb_sa, bsa, sa, 192, (size_t)PIX * 192); // offs+attn
  msda_k<<<dim3((BATCH * PIX * 16) / 256), blk, 0, stream>>>(s3, sa, s4);
  gemm2_k<0, false, 0><<<gF, blk, 0, stream>>>(s4, nullptr, wb_o, bo, s0, CH, OBS);               // xt_star
  gemm2_k<1, true , 0><<<gF, blk, 0, stream>>>(s0, s2, wb_t1, bt1, s1, CH, OBS);                  // h1
  gemm2_k<0, false, 0><<<gF, blk, 0, stream>>>(s1, nullptr, wb_t2, bt2, s3, CH, OBS);             // tg
  gemm2_k<2, true , 1><<<gF, blk, 0, stream>>>(s3, s2, wb_out, bout, d_out, PIX, (size_t)CH * PIX); // out
}

// Round 8
// 170.812 us; speedup vs baseline: 2.5228x; 2.5228x over previous
//
#include <hip/hip_runtime.h>
#include <math.h>

// ---------------------------------------------------------------------------
// TemporalGuidedModule round 8 = r7 GEMMs (coalesced staging, confirmed ~8us
// pipeline win) + r4 msda verbatim (natural 140 VGPR; r7's launch_bounds
// forced 64 VGPR -> 900MB scratch spill traffic, 290us. Reverted.)
// ---------------------------------------------------------------------------

#define PIX 16384
#define BATCH 2
#define CH 256

typedef short bf16x8 __attribute__((ext_vector_type(8)));
typedef float f32x4 __attribute__((ext_vector_type(4)));

__device__ __forceinline__ ushort f2bf(float f) {
  union { float f; unsigned u; } v; v.f = f;
  unsigned u = v.u;
  unsigned r = u + 0x7fffu + ((u >> 16) & 1u);   // RNE
  return (ushort)(r >> 16);
}
__device__ __forceinline__ float bfl(unsigned u) {
  union { unsigned u; float f; } v; v.u = u << 16; return v.f;
}
__device__ __forceinline__ float bfh(unsigned u) {
  union { unsigned u; float f; } v; v.u = u & 0xffff0000u; return v.f;
}
__device__ __forceinline__ unsigned fuse_u32(unsigned a, unsigned b, bool mul) {
  float rl = mul ? bfl(a) * bfl(b) : bfl(a) + bfl(b);
  float rh = mul ? bfh(a) * bfh(b) : bfh(a) + bfh(b);
  return (unsigned)f2bf(rl) | ((unsigned)f2bf(rh) << 16);
}

// --------------------------------------------------------------------------
// Weight prep + bias concat.
// --------------------------------------------------------------------------
__global__ __launch_bounds__(256) void wprep_k(
    const float* __restrict__ W_in1, const float* __restrict__ Wo,
    const float* __restrict__ Wt1, const float* __restrict__ Wt2,
    const float* __restrict__ Wout, const float* __restrict__ Ws,
    const float* __restrict__ Wa, const float* __restrict__ bs_off,
    const float* __restrict__ ba, ushort* __restrict__ wb,
    float* __restrict__ bsa)
{
  const int blk = blockIdx.x, k = threadIdx.x;
  if (blk >= 1472) {
    if (k < 128) bsa[k] = bs_off[k];
    else if (k < 192) bsa[k] = ba[k - 128];
    return;
  }
  const float* src;
  if (blk < 256) src = W_in1 + (size_t)blk * 256;
  else if (blk < 512) src = Wo + (size_t)(blk - 256) * 256;
  else if (blk < 768) src = Wt1 + (size_t)(blk - 512) * 256;
  else if (blk < 1024) src = Wt2 + (size_t)(blk - 768) * 256;
  else if (blk < 1280) src = Wout + (size_t)(blk - 1024) * 256;
  else if (blk < 1408) src = Ws + (size_t)(blk - 1280) * 256;
  else src = Wa + (size_t)(blk - 1408) * 256;
  wb[(size_t)blk * 256 + k] = f2bf(src[k]);
}

// Wv' = Wv @ W_in2 (bf16), bv' = Wv @ b_in2 + bv.
__global__ __launch_bounds__(256) void wvcomp_k(
    const float* __restrict__ Wv, const float* __restrict__ W_in2,
    const float* __restrict__ b_in2, const float* __restrict__ bv,
    ushort* __restrict__ Wvp, float* __restrict__ bvp)
{
  const int o = blockIdx.x, k = threadIdx.x;
  float acc = 0.f;
  #pragma unroll 8
  for (int c = 0; c < 256; ++c)
    acc += Wv[(size_t)o * 256 + c] * W_in2[(size_t)c * 256 + k];
  Wvp[(size_t)o * 256 + k] = f2bf(acc);
  __shared__ float red[256];
  red[k] = Wv[(size_t)o * 256 + k] * b_in2[k];
  __syncthreads();
  for (int s = 128; s > 0; s >>= 1) {
    if (k < s) red[k] += red[k + s];
    __syncthreads();
  }
  if (k == 0) bvp[o] = red[0] + bv[o];
}

// --------------------------------------------------------------------------
// Transpose-convert: [B][C][P] f32 -> [B][P][C] bf16.
// --------------------------------------------------------------------------
__global__ __launch_bounds__(256) void tconv_k(const float* __restrict__ in,
                                               ushort* __restrict__ out)
{
  __shared__ float t[32][33];
  const int tid = threadIdx.x;
  const int b = blockIdx.z;
  const int p0 = blockIdx.x * 32, c0 = blockIdx.y * 32;
  const int tx = tid & 31, ty = tid >> 5;
  const float* inb = in + (size_t)b * CH * PIX;
  #pragma unroll
  for (int i = 0; i < 4; ++i)
    t[ty + i * 8][tx] = inb[(size_t)(c0 + ty + i * 8) * PIX + p0 + tx];
  __syncthreads();
  const int cx = (tid & 15) * 2, py = tid >> 4;
  ushort* outb = out + (size_t)b * PIX * CH;
  #pragma unroll
  for (int i = 0; i < 2; ++i) {
    int pl = py + i * 16;
    unsigned lo = f2bf(t[cx][pl]);
    unsigned hi = f2bf(t[cx + 1][pl]);
    *(unsigned*)(outb + (size_t)(p0 + pl) * CH + c0 + cx) = lo | (hi << 16);
  }
}

// --------------------------------------------------------------------------
// MFMA GEMM (r7): 128p x 64o tile, BK=64, 4 waves, dbuf XOR-swizzled LDS.
// Coalesced staging: lane=(row=tid>>3 [+32/round], seg=tid&7) -> 8 lanes
// cover one full 128B line per instr.
// OMODE 0: pm bf16; 1: cm f32 (transposed bounce); 2: pm f32.
// FUSE 0 none; 1 x*=in2; 2 x+=in2 (in2 pm bf16).
// --------------------------------------------------------------------------
template<int FUSE, bool RELU, int OMODE>
__global__ __launch_bounds__(256, 3) void gemm2_k(
    const ushort* __restrict__ in, const ushort* __restrict__ in2,
    const ushort* __restrict__ Wb, const float* __restrict__ bias,
    void* __restrict__ out, int ldo, size_t obstride)
{
  __shared__ __align__(16) char smem[49152];
  const int tid = threadIdx.x;
  const int b = blockIdx.z;
  const int p0 = blockIdx.x * 128;
  const int o0 = blockIdx.y * 64;

  const ushort* inb = in + (size_t)b * PIX * CH;

  const int srow = tid >> 3, sseg = tid & 7;
  const int ssw = (srow & 7);
  const ushort* xsrc = inb + (size_t)(p0 + srow) * CH + sseg * 8;
  const ushort* x2src = (FUSE != 0)
      ? in2 + (size_t)b * PIX * CH + (size_t)(p0 + srow) * CH + sseg * 8
      : (const ushort*)nullptr;
  const ushort* wsrc = Wb + (size_t)(o0 + srow) * CH + sseg * 8;

  const int l = tid & 63, wv = tid >> 6;
  const int lr = l & 15, g4 = l >> 4;

  f32x4 acc[2][4];
  #pragma unroll
  for (int i = 0; i < 2; ++i)
    #pragma unroll
    for (int j = 0; j < 4; ++j) acc[i][j] = (f32x4){0.f, 0.f, 0.f, 0.f};

  uint4 xr[4], x2r[4], wr[2];

#define LOADT(kb)                                                              \
  {                                                                            \
    _Pragma("unroll")                                                          \
    for (int r = 0; r < 4; ++r)                                                \
      xr[r] = *(const uint4*)(xsrc + (kb) + (size_t)r * 32 * CH);              \
    if (FUSE != 0) {                                                           \
      _Pragma("unroll")                                                        \
      for (int r = 0; r < 4; ++r)                                              \
        x2r[r] = *(const uint4*)(x2src + (kb) + (size_t)r * 32 * CH);          \
    }                                                                          \
    _Pragma("unroll")                                                          \
    for (int r = 0; r < 2; ++r)                                                \
      wr[r] = *(const uint4*)(wsrc + (kb) + (size_t)r * 32 * CH);              \
  }

#define WRITET(buf)                                                            \
  {                                                                            \
    _Pragma("unroll")                                                          \
    for (int r = 0; r < 4; ++r) {                                              \
      uint4 v = xr[r];                                                         \
      if (FUSE != 0) {                                                         \
        unsigned* pa = (unsigned*)&v;                                          \
        const unsigned* pb = (const unsigned*)&x2r[r];                         \
        _Pragma("unroll")                                                      \
        for (int w = 0; w < 4; ++w) pa[w] = fuse_u32(pa[w], pb[w], FUSE == 1); \
      }                                                                        \
      *(uint4*)(smem + (buf) * 16384 + (srow + r * 32) * 128 +                 \
                ((sseg ^ ssw) * 16)) = v;                                      \
    }                                                                          \
    _Pragma("unroll")                                                          \
    for (int r = 0; r < 2; ++r)                                                \
      *(uint4*)(smem + 32768 + (buf) * 8192 + (srow + r * 32) * 128 +          \
                ((sseg ^ ssw) * 16)) = wr[r];                                  \
  }

  LOADT(0)
  WRITET(0)
  __syncthreads();

  for (int t = 0; t < 4; ++t) {
    if (t < 3) LOADT((t + 1) * 64)
    const char* XB = smem + (t & 1) * 16384;
    const char* WB = smem + 32768 + (t & 1) * 8192;
    bf16x8 af[2][2], bfr[4][2];
    #pragma unroll
    for (int fm = 0; fm < 2; ++fm) {
      const int p = wv * 32 + fm * 16 + lr;
      #pragma unroll
      for (int kh = 0; kh < 2; ++kh)
        af[fm][kh] = *(const bf16x8*)(XB + p * 128 + (((kh * 4 + g4) ^ (p & 7)) * 16));
    }
    #pragma unroll
    for (int fn = 0; fn < 4; ++fn) {
      const int o = fn * 16 + lr;
      #pragma unroll
      for (int kh = 0; kh < 2; ++kh)
        bfr[fn][kh] = *(const bf16x8*)(WB + o * 128 + (((kh * 4 + g4) ^ (o & 7)) * 16));
    }
    #pragma unroll
    for (int fm = 0; fm < 2; ++fm)
      #pragma unroll
      for (int fn = 0; fn < 4; ++fn) {
        acc[fm][fn] = __builtin_amdgcn_mfma_f32_16x16x32_bf16(af[fm][0], bfr[fn][0], acc[fm][fn], 0, 0, 0);
        acc[fm][fn] = __builtin_amdgcn_mfma_f32_16x16x32_bf16(af[fm][1], bfr[fn][1], acc[fm][fn], 0, 0, 0);
      }
    if (t < 3) WRITET((t + 1) & 1)
    __syncthreads();
  }
#undef LOADT
#undef WRITET

  // ---- epilogue ---- C/D: col(o) = lr, row(p) = g4*4 + reg
  float bvv[4];
  #pragma unroll
  for (int fn = 0; fn < 4; ++fn) bvv[fn] = bias[o0 + fn * 16 + lr];

  if (OMODE == 1) {               // cm f32 via TRANSPOSED bounce El2[64][132] f32
    float* El2 = (float*)smem;
    #pragma unroll
    for (int fm = 0; fm < 2; ++fm)
      #pragma unroll
      for (int fn = 0; fn < 4; ++fn) {
        float4 v;
        v.x = acc[fm][fn][0] + bvv[fn]; v.y = acc[fm][fn][1] + bvv[fn];
        v.z = acc[fm][fn][2] + bvv[fn]; v.w = acc[fm][fn][3] + bvv[fn];
        if (RELU) {
          v.x = fmaxf(v.x, 0.f); v.y = fmaxf(v.y, 0.f);
          v.z = fmaxf(v.z, 0.f); v.w = fmaxf(v.w, 0.f);
        }
        *(float4*)&El2[(size_t)(fn * 16 + lr) * 132 + wv * 32 + fm * 16 + g4 * 4] = v;
      }
    __syncthreads();
    float* outb = (float*)out + (size_t)b * obstride;
    const int og = tid >> 5, seg = tid & 31;
    #pragma unroll
    for (int r = 0; r < 8; ++r) {
      const int orow = og + r * 8;
      float4 v = *(float4*)(smem + orow * 528 + seg * 16);
      *(float4*)(outb + (size_t)(o0 + orow) * ldo + p0 + seg * 4) = v;
    }
  } else if (OMODE == 0) {        // pm bf16 via LDS bounce [128][72] halves
    ushort* El = (ushort*)smem;
    #pragma unroll
    for (int fm = 0; fm < 2; ++fm)
      #pragma unroll
      for (int fn = 0; fn < 4; ++fn)
        #pragma unroll
        for (int r = 0; r < 4; ++r) {
          const int p = wv * 32 + fm * 16 + g4 * 4 + r;
          float v = acc[fm][fn][r] + bvv[fn];
          if (RELU) v = fmaxf(v, 0.f);
          El[p * 72 + fn * 16 + lr] = f2bf(v);
        }
    __syncthreads();
    ushort* outb = (ushort*)out + (size_t)b * obstride;
    const int rg = tid >> 3, seg = tid & 7;
    #pragma unroll
    for (int r = 0; r < 4; ++r) {
      const int row = rg + r * 32;
      uint4 v = *(uint4*)(smem + row * 144 + seg * 16);
      *(uint4*)(outb + (size_t)(p0 + row) * ldo + o0 + seg * 8) = v;
    }
  } else {                        // OMODE 2: pm f32 via LDS bounce [128][68] f32
    float* El = (float*)smem;
    #pragma unroll
    for (int fm = 0; fm < 2; ++fm)
      #pragma unroll
      for (int fn = 0; fn < 4; ++fn)
        #pragma unroll
        for (int r = 0; r < 4; ++r) {
          const int p = wv * 32 + fm * 16 + g4 * 4 + r;
          float v = acc[fm][fn][r] + bvv[fn];
          if (RELU) v = fmaxf(v, 0.f);
          El[p * 68 + fn * 16 + lr] = v;
        }
    __syncthreads();
    float* outb = (float*)out + (size_t)b * obstride;
    const int rg = tid >> 4, seg = tid & 15;
    #pragma unroll
    for (int r = 0; r < 8; ++r) {
      const int row = rg + r * 16;
      float4 v = *(float4*)(smem + row * 272 + seg * 16);
      *(float4*)(outb + (size_t)(p0 + row) * ldo + o0 + seg * 4) = v;
    }
  }
}

// --------------------------------------------------------------------------
// Fused MSDA — r4 verbatim (natural register allocation, ~140 VGPR).
// value pm bf16 [B][P][256]; sa sample-major f32 [B][P][192]; out pm bf16.
// --------------------------------------------------------------------------
__global__ __launch_bounds__(256) void msda_k(
    const ushort* __restrict__ value, const float* __restrict__ sa,
    ushort* __restrict__ out)
{
  const int t = blockIdx.x * 256 + threadIdx.x;   // B*P*16
  const int dh = t & 1;
  const int h = (t >> 1) & 7;
  const int pg = t >> 4;
  const int b = pg >> 14;
  const int p = pg & (PIX - 1);
  const int px = p & 127, py = p >> 7;

  const ushort* vb = value + (size_t)b * PIX * CH;
  const float* sp = sa + (size_t)pg * 192;

  float4 la = *(const float4*)(sp + 128 + h * 8);
  float4 lb = *(const float4*)(sp + 128 + h * 8 + 4);
  float lg[8] = {la.x, la.y, la.z, la.w, lb.x, lb.y, lb.z, lb.w};
  float m = lg[0];
  #pragma unroll
  for (int i = 1; i < 8; ++i) m = fmaxf(m, lg[i]);
  float s = 0.f;
  #pragma unroll
  for (int i = 0; i < 8; ++i) { lg[i] = __expf(lg[i] - m); s += lg[i]; }
  const float inv = 1.f / s;

  float of[16];
  #pragma unroll
  for (int j = 0; j < 4; ++j)
    *(float4*)&of[j * 4] = *(const float4*)(sp + h * 16 + j * 4);

  float acc[16];
  #pragma unroll
  for (int i = 0; i < 16; ++i) acc[i] = 0.f;

  #pragma unroll
  for (int pt = 0; pt < 8; ++pt) {
    const float ox = of[2 * pt], oy = of[2 * pt + 1];
    const float aw = lg[pt] * inv;
    const float ix = px + ox, iy = py + oy;   // grid_sample -0.5 cancels
    const float xf = floorf(ix), yf = floorf(iy);
    const float fx = ix - xf, fy = iy - yf;
    const int x0 = (int)xf, y0 = (int)yf;
    #pragma unroll
    for (int cr = 0; cr < 4; ++cr) {
      const int dx = cr & 1, dy = cr >> 1;
      const int xx = x0 + dx, yy = y0 + dy;
      const float wx = dx ? fx : (1.f - fx);
      const float wy = dy ? fy : (1.f - fy);
      const bool valid = ((unsigned)xx < 128u) & ((unsigned)yy < 128u);
      float w = valid ? (wx * wy * aw) : 0.f;
      const int xc = min(max(xx, 0), 127), yc = min(max(yy, 0), 127);
      const ushort* vr = vb + ((size_t)(yc * 128 + xc) * CH + h * 32 + dh * 16);
      uint4 q0 = *(const uint4*)vr;
      uint4 q1 = *(const uint4*)(vr + 8);
      const unsigned* qw0 = (const unsigned*)&q0;
      const unsigned* qw1 = (const unsigned*)&q1;
      #pragma unroll
      for (int ww = 0; ww < 4; ++ww) {
        acc[2 * ww + 0] = fmaf(w, bfl(qw0[ww]), acc[2 * ww + 0]);
        acc[2 * ww + 1] = fmaf(w, bfh(qw0[ww]), acc[2 * ww + 1]);
        acc[8 + 2 * ww + 0] = fmaf(w, bfl(qw1[ww]), acc[8 + 2 * ww + 0]);
        acc[8 + 2 * ww + 1] = fmaf(w, bfh(qw1[ww]), acc[8 + 2 * ww + 1]);
      }
    }
  }
  unsigned r[8];
  #pragma unroll
  for (int k = 0; k < 8; ++k)
    r[k] = (unsigned)f2bf(acc[2 * k]) | ((unsigned)f2bf(acc[2 * k + 1]) << 16);
  ushort* dst = out + (size_t)pg * CH + h * 32 + dh * 16;
  *(uint4*)dst = *(uint4*)&r[0];
  *(uint4*)(dst + 8) = *(uint4*)&r[4];
}

extern "C" void kernel_launch(void* const* d_in, const int* in_sizes, int n_in,
                              void* d_out, int out_size, void* d_ws, size_t ws_size,
                              hipStream_t stream)
{
  const float* xt     = (const float*)d_in[0];
  const float* xt_1   = (const float*)d_in[1];
  const float* W_in1  = (const float*)d_in[2];
  const float* b_in1  = (const float*)d_in[3];
  const float* W_in2  = (const float*)d_in[4];
  const float* b_in2  = (const float*)d_in[5];
  const float* Wv     = (const float*)d_in[6];
  const float* bv     = (const float*)d_in[7];
  const float* Ws     = (const float*)d_in[8];
  const float* bs_off = (const float*)d_in[9];
  const float* Wa     = (const float*)d_in[10];
  const float* ba     = (const float*)d_in[11];
  const float* Wo     = (const float*)d_in[12];
  const float* bo     = (const float*)d_in[13];
  const float* Wt1    = (const float*)d_in[14];
  const float* bt1    = (const float*)d_in[15];
  const float* Wt2    = (const float*)d_in[16];
  const float* bt2    = (const float*)d_in[17];
  const float* Wout   = (const float*)d_in[18];
  const float* bout   = (const float*)d_in[19];

  char* ws = (char*)d_ws;
  const size_t SLOT = (size_t)BATCH * PIX * CH * 2;          // 16.78 MB
  const size_t SAB  = (size_t)BATCH * PIX * 192 * 4;         // 25.17 MB
  ushort* s0 = (ushort*)(ws + 0 * SLOT);   // xt_pm  -> xt_star
  ushort* s1 = (ushort*)(ws + 1 * SLOT);   // xt1_pm -> h1
  ushort* s2 = (ushort*)(ws + 2 * SLOT);   // x1 (live to end)
  ushort* s3 = (ushort*)(ws + 3 * SLOT);   // value  -> tg
  ushort* s4 = (ushort*)(ws + 4 * SLOT);   // msda_out
  float*  sa = (float*)(ws + 5 * SLOT);    // [B][P][192] offs+attn
  char* wbase = ws + 5 * SLOT + SAB;
  ushort* wb  = (ushort*)wbase;            // 1472x256 bf16
  ushort* wvp = (ushort*)(wbase + (size_t)1472 * 256 * 2);   // 256x256 bf16
  float* bsa  = (float*)(wbase + (size_t)1472 * 256 * 2 + (size_t)256 * 256 * 2);
  float* bvp  = bsa + 192;

  ushort* wb_in1 = wb;
  ushort* wb_o   = wb + 65536;
  ushort* wb_t1  = wb + 131072;
  ushort* wb_t2  = wb + 196608;
  ushort* wb_out = wb + 262144;
  ushort* wb_sa  = wb + 327680;            // 192 rows: Ws then Wa

  dim3 blk(256);
  dim3 gT(PIX / 32, CH / 32, BATCH);
  dim3 gF(PIX / 128, 4, BATCH);            // Cout=256
  dim3 gS(PIX / 128, 3, BATCH);            // Cout=192
  const size_t OBS = (size_t)PIX * CH;     // pm bf16 batch stride (elems)

  wprep_k<<<1473, blk, 0, stream>>>(W_in1, Wo, Wt1, Wt2, Wout, Ws, Wa, bs_off, ba, wb, bsa);
  wvcomp_k<<<256, blk, 0, stream>>>(Wv, W_in2, b_in2, bv, wvp, bvp);
  tconv_k<<<gT, blk, 0, stream>>>(xt, s0);
  tconv_k<<<gT, blk, 0, stream>>>(xt_1, s1);

  gemm2_k<0, false, 0><<<gF, blk, 0, stream>>>(s0, nullptr, wb_in1, b_in1, s2, CH, OBS);          // x1
  gemm2_k<0, false, 0><<<gF, blk, 0, stream>>>(s1, nullptr, wvp, bvp, s3, CH, OBS);               // value
  gemm2_k<0, false, 2><<<gS, blk, 0, stream>>>(s2, nullptr, wb_sa, bsa, sa, 192, (size_t)PIX * 192); // offs+attn
  msda_k<<<dim3((BATCH * PIX * 16) / 256), blk, 0, stream>>>(s3, sa, s4);
  gemm2_k<0, false, 0><<<gF, blk, 0, stream>>>(s4, nullptr, wb_o, bo, s0, CH, OBS);               // xt_star
  gemm2_k<1, true , 0><<<gF, blk, 0, stream>>>(s0, s2, wb_t1, bt1, s1, CH, OBS);                  // h1
  gemm2_k<0, false, 0><<<gF, blk, 0, stream>>>(s1, nullptr, wb_t2, bt2, s3, CH, OBS);             // tg
  gemm2_k<2, true , 1><<<gF, blk, 0, stream>>>(s3, s2, wb_out, bout, d_out, PIX, (size_t)CH * PIX); // out
}

// Round 9
// 164.931 us; speedup vs baseline: 2.6128x; 1.0357x over previous
//
#include <hip/hip_runtime.h>
#include <math.h>

// ---------------------------------------------------------------------------
// TemporalGuidedModule round 9 = r8 + global_load_lds staging for FUSE=0 GEMMs.
//  - FUSE=0 staging: direct global->LDS DMA (width 16), LDS dest lane-linear,
//    XOR swizzle moved to the per-lane GLOBAL source address (m173 pattern).
//    Read side unchanged (involution composes the same).
//  - FUSE!=0 (h1, out) keep the register staging path (elementwise fuse).
//  - tconv merged into one launch (z = input*2 + batch).
// ---------------------------------------------------------------------------

#define PIX 16384
#define BATCH 2
#define CH 256

typedef short bf16x8 __attribute__((ext_vector_type(8)));
typedef float f32x4 __attribute__((ext_vector_type(4)));

typedef const __attribute__((address_space(1))) void* as1cv;
typedef __attribute__((address_space(3))) void* as3v;
__device__ __forceinline__ void gl_lds16(const void* g, void* l) {
  __builtin_amdgcn_global_load_lds((as1cv)g, (as3v)l, 16, 0, 0);
}

__device__ __forceinline__ ushort f2bf(float f) {
  union { float f; unsigned u; } v; v.f = f;
  unsigned u = v.u;
  unsigned r = u + 0x7fffu + ((u >> 16) & 1u);   // RNE
  return (ushort)(r >> 16);
}
__device__ __forceinline__ float bfl(unsigned u) {
  union { unsigned u; float f; } v; v.u = u << 16; return v.f;
}
__device__ __forceinline__ float bfh(unsigned u) {
  union { unsigned u; float f; } v; v.u = u & 0xffff0000u; return v.f;
}
__device__ __forceinline__ unsigned fuse_u32(unsigned a, unsigned b, bool mul) {
  float rl = mul ? bfl(a) * bfl(b) : bfl(a) + bfl(b);
  float rh = mul ? bfh(a) * bfh(b) : bfh(a) + bfh(b);
  return (unsigned)f2bf(rl) | ((unsigned)f2bf(rh) << 16);
}

// --------------------------------------------------------------------------
// Weight prep + bias concat.
// --------------------------------------------------------------------------
__global__ __launch_bounds__(256) void wprep_k(
    const float* __restrict__ W_in1, const float* __restrict__ Wo,
    const float* __restrict__ Wt1, const float* __restrict__ Wt2,
    const float* __restrict__ Wout, const float* __restrict__ Ws,
    const float* __restrict__ Wa, const float* __restrict__ bs_off,
    const float* __restrict__ ba, ushort* __restrict__ wb,
    float* __restrict__ bsa)
{
  const int blk = blockIdx.x, k = threadIdx.x;
  if (blk >= 1472) {
    if (k < 128) bsa[k] = bs_off[k];
    else if (k < 192) bsa[k] = ba[k - 128];
    return;
  }
  const float* src;
  if (blk < 256) src = W_in1 + (size_t)blk * 256;
  else if (blk < 512) src = Wo + (size_t)(blk - 256) * 256;
  else if (blk < 768) src = Wt1 + (size_t)(blk - 512) * 256;
  else if (blk < 1024) src = Wt2 + (size_t)(blk - 768) * 256;
  else if (blk < 1280) src = Wout + (size_t)(blk - 1024) * 256;
  else if (blk < 1408) src = Ws + (size_t)(blk - 1280) * 256;
  else src = Wa + (size_t)(blk - 1408) * 256;
  wb[(size_t)blk * 256 + k] = f2bf(src[k]);
}

// Wv' = Wv @ W_in2 (bf16), bv' = Wv @ b_in2 + bv.
__global__ __launch_bounds__(256) void wvcomp_k(
    const float* __restrict__ Wv, const float* __restrict__ W_in2,
    const float* __restrict__ b_in2, const float* __restrict__ bv,
    ushort* __restrict__ Wvp, float* __restrict__ bvp)
{
  const int o = blockIdx.x, k = threadIdx.x;
  float acc = 0.f;
  #pragma unroll 8
  for (int c = 0; c < 256; ++c)
    acc += Wv[(size_t)o * 256 + c] * W_in2[(size_t)c * 256 + k];
  Wvp[(size_t)o * 256 + k] = f2bf(acc);
  __shared__ float red[256];
  red[k] = Wv[(size_t)o * 256 + k] * b_in2[k];
  __syncthreads();
  for (int s = 128; s > 0; s >>= 1) {
    if (k < s) red[k] += red[k + s];
    __syncthreads();
  }
  if (k == 0) bvp[o] = red[0] + bv[o];
}

// --------------------------------------------------------------------------
// Transpose-convert x2: z = (input<<1)|batch. [B][C][P] f32 -> [B][P][C] bf16.
// --------------------------------------------------------------------------
__global__ __launch_bounds__(256) void tconv2_k(
    const float* __restrict__ inA, const float* __restrict__ inB,
    ushort* __restrict__ outA, ushort* __restrict__ outB)
{
  __shared__ float t[32][33];
  const int tid = threadIdx.x;
  const int z = blockIdx.z;
  const int b = z & 1;
  const float* in = (z < 2) ? inA : inB;
  ushort* out = (z < 2) ? outA : outB;
  const int p0 = blockIdx.x * 32, c0 = blockIdx.y * 32;
  const int tx = tid & 31, ty = tid >> 5;
  const float* inb = in + (size_t)b * CH * PIX;
  #pragma unroll
  for (int i = 0; i < 4; ++i)
    t[ty + i * 8][tx] = inb[(size_t)(c0 + ty + i * 8) * PIX + p0 + tx];
  __syncthreads();
  const int cx = (tid & 15) * 2, py = tid >> 4;
  ushort* outb = out + (size_t)b * PIX * CH;
  #pragma unroll
  for (int i = 0; i < 2; ++i) {
    int pl = py + i * 16;
    unsigned lo = f2bf(t[cx][pl]);
    unsigned hi = f2bf(t[cx + 1][pl]);
    *(unsigned*)(outb + (size_t)(p0 + pl) * CH + c0 + cx) = lo | (hi << 16);
  }
}

// --------------------------------------------------------------------------
// MFMA GEMM: 128p x 64o tile, BK=64, 4 waves, dbuf XOR-swizzled LDS.
// FUSE=0: global_load_lds staging (LDS lane-linear, source pre-swizzled).
// FUSE!=0: register staging with fused elementwise (r8 path).
// OMODE 0: pm bf16; 1: cm f32 (transposed bounce); 2: pm f32.
// --------------------------------------------------------------------------
template<int FUSE, bool RELU, int OMODE>
__global__ __launch_bounds__(256, 3) void gemm2_k(
    const ushort* __restrict__ in, const ushort* __restrict__ in2,
    const ushort* __restrict__ Wb, const float* __restrict__ bias,
    void* __restrict__ out, int ldo, size_t obstride)
{
  __shared__ __align__(16) char smem[49152];
  const int tid = threadIdx.x;
  const int b = blockIdx.z;
  const int p0 = blockIdx.x * 128;
  const int o0 = blockIdx.y * 64;

  const ushort* inb = in + (size_t)b * PIX * CH;

  const int srow = tid >> 3, sseg = tid & 7;
  const int ssw = (srow & 7);
  // FUSE=0: swizzle on the GLOBAL source; LDS dest lane-linear (tid*16).
  // FUSE!=0: linear source; swizzle on the LDS write (r8 path).
  const int gseg = (FUSE == 0) ? (sseg ^ ssw) : sseg;
  const ushort* xsrc = inb + (size_t)(p0 + srow) * CH + gseg * 8;
  const ushort* x2src = (FUSE != 0)
      ? in2 + (size_t)b * PIX * CH + (size_t)(p0 + srow) * CH + sseg * 8
      : (const ushort*)nullptr;
  const ushort* wsrc = Wb + (size_t)(o0 + srow) * CH + gseg * 8;

  const int l = tid & 63, wv = tid >> 6;
  const int lr = l & 15, g4 = l >> 4;

  f32x4 acc[2][4];
  #pragma unroll
  for (int i = 0; i < 2; ++i)
    #pragma unroll
    for (int j = 0; j < 4; ++j) acc[i][j] = (f32x4){0.f, 0.f, 0.f, 0.f};

  uint4 xr[4], x2r[4], wr[2];

// ---- FUSE=0: async DMA staging ----
#define STAGE_GLL(buf, kb)                                                     \
  {                                                                            \
    _Pragma("unroll")                                                          \
    for (int r = 0; r < 4; ++r)                                                \
      gl_lds16(xsrc + (kb) + (size_t)r * 32 * CH,                              \
               smem + (buf) * 16384 + r * 4096 + tid * 16);                    \
    _Pragma("unroll")                                                          \
    for (int r = 0; r < 2; ++r)                                                \
      gl_lds16(wsrc + (kb) + (size_t)r * 32 * CH,                              \
               smem + 32768 + (buf) * 8192 + r * 4096 + tid * 16);             \
  }

// ---- FUSE!=0: register staging ----
#define LOADT(kb)                                                              \
  {                                                                            \
    _Pragma("unroll")                                                          \
    for (int r = 0; r < 4; ++r)                                                \
      xr[r] = *(const uint4*)(xsrc + (kb) + (size_t)r * 32 * CH);              \
    _Pragma("unroll")                                                          \
    for (int r = 0; r < 4; ++r)                                                \
      x2r[r] = *(const uint4*)(x2src + (kb) + (size_t)r * 32 * CH);            \
    _Pragma("unroll")                                                          \
    for (int r = 0; r < 2; ++r)                                                \
      wr[r] = *(const uint4*)(wsrc + (kb) + (size_t)r * 32 * CH);              \
  }

#define WRITET(buf)                                                            \
  {                                                                            \
    _Pragma("unroll")                                                          \
    for (int r = 0; r < 4; ++r) {                                              \
      uint4 v = xr[r];                                                         \
      unsigned* pa = (unsigned*)&v;                                            \
      const unsigned* pb = (const unsigned*)&x2r[r];                           \
      _Pragma("unroll")                                                        \
      for (int w = 0; w < 4; ++w) pa[w] = fuse_u32(pa[w], pb[w], FUSE == 1);   \
      *(uint4*)(smem + (buf) * 16384 + (srow + r * 32) * 128 +                 \
                ((sseg ^ ssw) * 16)) = v;                                      \
    }                                                                          \
    _Pragma("unroll")                                                          \
    for (int r = 0; r < 2; ++r)                                                \
      *(uint4*)(smem + 32768 + (buf) * 8192 + (srow + r * 32) * 128 +          \
                ((sseg ^ ssw) * 16)) = wr[r];                                  \
  }

  if (FUSE == 0) { STAGE_GLL(0, 0) }
  else           { LOADT(0) WRITET(0) }
  __syncthreads();

  for (int t = 0; t < 4; ++t) {
    if (t < 3) {
      if (FUSE == 0) { STAGE_GLL((t + 1) & 1, (t + 1) * 64) }
      else           { LOADT((t + 1) * 64) }
    }
    const char* XB = smem + (t & 1) * 16384;
    const char* WB = smem + 32768 + (t & 1) * 8192;
    bf16x8 af[2][2], bfr[4][2];
    #pragma unroll
    for (int fm = 0; fm < 2; ++fm) {
      const int p = wv * 32 + fm * 16 + lr;
      #pragma unroll
      for (int kh = 0; kh < 2; ++kh)
        af[fm][kh] = *(const bf16x8*)(XB + p * 128 + (((kh * 4 + g4) ^ (p & 7)) * 16));
    }
    #pragma unroll
    for (int fn = 0; fn < 4; ++fn) {
      const int o = fn * 16 + lr;
      #pragma unroll
      for (int kh = 0; kh < 2; ++kh)
        bfr[fn][kh] = *(const bf16x8*)(WB + o * 128 + (((kh * 4 + g4) ^ (o & 7)) * 16));
    }
    #pragma unroll
    for (int fm = 0; fm < 2; ++fm)
      #pragma unroll
      for (int fn = 0; fn < 4; ++fn) {
        acc[fm][fn] = __builtin_amdgcn_mfma_f32_16x16x32_bf16(af[fm][0], bfr[fn][0], acc[fm][fn], 0, 0, 0);
        acc[fm][fn] = __builtin_amdgcn_mfma_f32_16x16x32_bf16(af[fm][1], bfr[fn][1], acc[fm][fn], 0, 0, 0);
      }
    if (t < 3 && FUSE != 0) { WRITET((t + 1) & 1) }
    __syncthreads();
  }
#undef STAGE_GLL
#undef LOADT
#undef WRITET

  // ---- epilogue ---- C/D: col(o) = lr, row(p) = g4*4 + reg
  float bvv[4];
  #pragma unroll
  for (int fn = 0; fn < 4; ++fn) bvv[fn] = bias[o0 + fn * 16 + lr];

  if (OMODE == 1) {               // cm f32 via TRANSPOSED bounce El2[64][132] f32
    float* El2 = (float*)smem;
    #pragma unroll
    for (int fm = 0; fm < 2; ++fm)
      #pragma unroll
      for (int fn = 0; fn < 4; ++fn) {
        float4 v;
        v.x = acc[fm][fn][0] + bvv[fn]; v.y = acc[fm][fn][1] + bvv[fn];
        v.z = acc[fm][fn][2] + bvv[fn]; v.w = acc[fm][fn][3] + bvv[fn];
        if (RELU) {
          v.x = fmaxf(v.x, 0.f); v.y = fmaxf(v.y, 0.f);
          v.z = fmaxf(v.z, 0.f); v.w = fmaxf(v.w, 0.f);
        }
        *(float4*)&El2[(size_t)(fn * 16 + lr) * 132 + wv * 32 + fm * 16 + g4 * 4] = v;
      }
    __syncthreads();
    float* outb = (float*)out + (size_t)b * obstride;
    const int og = tid >> 5, seg = tid & 31;
    #pragma unroll
    for (int r = 0; r < 8; ++r) {
      const int orow = og + r * 8;
      float4 v = *(float4*)(smem + orow * 528 + seg * 16);
      *(float4*)(outb + (size_t)(o0 + orow) * ldo + p0 + seg * 4) = v;
    }
  } else if (OMODE == 0) {        // pm bf16 via LDS bounce [128][72] halves
    ushort* El = (ushort*)smem;
    #pragma unroll
    for (int fm = 0; fm < 2; ++fm)
      #pragma unroll
      for (int fn = 0; fn < 4; ++fn)
        #pragma unroll
        for (int r = 0; r < 4; ++r) {
          const int p = wv * 32 + fm * 16 + g4 * 4 + r;
          float v = acc[fm][fn][r] + bvv[fn];
          if (RELU) v = fmaxf(v, 0.f);
          El[p * 72 + fn * 16 + lr] = f2bf(v);
        }
    __syncthreads();
    ushort* outb = (ushort*)out + (size_t)b * obstride;
    const int rg = tid >> 3, seg = tid & 7;
    #pragma unroll
    for (int r = 0; r < 4; ++r) {
      const int row = rg + r * 32;
      uint4 v = *(uint4*)(smem + row * 144 + seg * 16);
      *(uint4*)(outb + (size_t)(p0 + row) * ldo + o0 + seg * 8) = v;
    }
  } else {                        // OMODE 2: pm f32 via LDS bounce [128][68] f32
    float* El = (float*)smem;
    #pragma unroll
    for (int fm = 0; fm < 2; ++fm)
      #pragma unroll
      for (int fn = 0; fn < 4; ++fn)
        #pragma unroll
        for (int r = 0; r < 4; ++r) {
          const int p = wv * 32 + fm * 16 + g4 * 4 + r;
          float v = acc[fm][fn][r] + bvv[fn];
          if (RELU) v = fmaxf(v, 0.f);
          El[p * 68 + fn * 16 + lr] = v;
        }
    __syncthreads();
    float* outb = (float*)out + (size_t)b * obstride;
    const int rg = tid >> 4, seg = tid & 15;
    #pragma unroll
    for (int r = 0; r < 8; ++r) {
      const int row = rg + r * 16;
      float4 v = *(float4*)(smem + row * 272 + seg * 16);
      *(float4*)(outb + (size_t)(p0 + row) * ldo + o0 + seg * 4) = v;
    }
  }
}

// --------------------------------------------------------------------------
// Fused MSDA — r4/r8 verbatim (natural register allocation, ~140 VGPR).
// --------------------------------------------------------------------------
__global__ __launch_bounds__(256) void msda_k(
    const ushort* __restrict__ value, const float* __restrict__ sa,
    ushort* __restrict__ out)
{
  const int t = blockIdx.x * 256 + threadIdx.x;   // B*P*16
  const int dh = t & 1;
  const int h = (t >> 1) & 7;
  const int pg = t >> 4;
  const int b = pg >> 14;
  const int p = pg & (PIX - 1);
  const int px = p & 127, py = p >> 7;

  const ushort* vb = value + (size_t)b * PIX * CH;
  const float* sp = sa + (size_t)pg * 192;

  float4 la = *(const float4*)(sp + 128 + h * 8);
  float4 lb = *(const float4*)(sp + 128 + h * 8 + 4);
  float lg[8] = {la.x, la.y, la.z, la.w, lb.x, lb.y, lb.z, lb.w};
  float m = lg[0];
  #pragma unroll
  for (int i = 1; i < 8; ++i) m = fmaxf(m, lg[i]);
  float s = 0.f;
  #pragma unroll
  for (int i = 0; i < 8; ++i) { lg[i] = __expf(lg[i] - m); s += lg[i]; }
  const float inv = 1.f / s;

  float of[16];
  #pragma unroll
  for (int j = 0; j < 4; ++j)
    *(float4*)&of[j * 4] = *(const float4*)(sp + h * 16 + j * 4);

  float acc[16];
  #pragma unroll
  for (int i = 0; i < 16; ++i) acc[i] = 0.f;

  #pragma unroll
  for (int pt = 0; pt < 8; ++pt) {
    const float ox = of[2 * pt], oy = of[2 * pt + 1];
    const float aw = lg[pt] * inv;
    const float ix = px + ox, iy = py + oy;   // grid_sample -0.5 cancels
    const float xf = floorf(ix), yf = floorf(iy);
    const float fx = ix - xf, fy = iy - yf;
    const int x0 = (int)xf, y0 = (int)yf;
    #pragma unroll
    for (int cr = 0; cr < 4; ++cr) {
      const int dx = cr & 1, dy = cr >> 1;
      const int xx = x0 + dx, yy = y0 + dy;
      const float wx = dx ? fx : (1.f - fx);
      const float wy = dy ? fy : (1.f - fy);
      const bool valid = ((unsigned)xx < 128u) & ((unsigned)yy < 128u);
      float w = valid ? (wx * wy * aw) : 0.f;
      const int xc = min(max(xx, 0), 127), yc = min(max(yy, 0), 127);
      const ushort* vr = vb + ((size_t)(yc * 128 + xc) * CH + h * 32 + dh * 16);
      uint4 q0 = *(const uint4*)vr;
      uint4 q1 = *(const uint4*)(vr + 8);
      const unsigned* qw0 = (const unsigned*)&q0;
      const unsigned* qw1 = (const unsigned*)&q1;
      #pragma unroll
      for (int ww = 0; ww < 4; ++ww) {
        acc[2 * ww + 0] = fmaf(w, bfl(qw0[ww]), acc[2 * ww + 0]);
        acc[2 * ww + 1] = fmaf(w, bfh(qw0[ww]), acc[2 * ww + 1]);
        acc[8 + 2 * ww + 0] = fmaf(w, bfl(qw1[ww]), acc[8 + 2 * ww + 0]);
        acc[8 + 2 * ww + 1] = fmaf(w, bfh(qw1[ww]), acc[8 + 2 * ww + 1]);
      }
    }
  }
  unsigned r[8];
  #pragma unroll
  for (int k = 0; k < 8; ++k)
    r[k] = (unsigned)f2bf(acc[2 * k]) | ((unsigned)f2bf(acc[2 * k + 1]) << 16);
  ushort* dst = out + (size_t)pg * CH + h * 32 + dh * 16;
  *(uint4*)dst = *(uint4*)&r[0];
  *(uint4*)(dst + 8) = *(uint4*)&r[4];
}

extern "C" void kernel_launch(void* const* d_in, const int* in_sizes, int n_in,
                              void* d_out, int out_size, void* d_ws, size_t ws_size,
                              hipStream_t stream)
{
  const float* xt     = (const float*)d_in[0];
  const float* xt_1   = (const float*)d_in[1];
  const float* W_in1  = (const float*)d_in[2];
  const float* b_in1  = (const float*)d_in[3];
  const float* W_in2  = (const float*)d_in[4];
  const float* b_in2  = (const float*)d_in[5];
  const float* Wv     = (const float*)d_in[6];
  const float* bv     = (const float*)d_in[7];
  const float* Ws     = (const float*)d_in[8];
  const float* bs_off = (const float*)d_in[9];
  const float* Wa     = (const float*)d_in[10];
  const float* ba     = (const float*)d_in[11];
  const float* Wo     = (const float*)d_in[12];
  const float* bo     = (const float*)d_in[13];
  const float* Wt1    = (const float*)d_in[14];
  const float* bt1    = (const float*)d_in[15];
  const float* Wt2    = (const float*)d_in[16];
  const float* bt2    = (const float*)d_in[17];
  const float* Wout   = (const float*)d_in[18];
  const float* bout   = (const float*)d_in[19];

  char* ws = (char*)d_ws;
  const size_t SLOT = (size_t)BATCH * PIX * CH * 2;          // 16.78 MB
  const size_t SAB  = (size_t)BATCH * PIX * 192 * 4;         // 25.17 MB
  ushort* s0 = (ushort*)(ws + 0 * SLOT);   // xt_pm  -> xt_star
  ushort* s1 = (ushort*)(ws + 1 * SLOT);   // xt1_pm -> h1
  ushort* s2 = (ushort*)(ws + 2 * SLOT);   // x1 (live to end)
  ushort* s3 = (ushort*)(ws + 3 * SLOT);   // value  -> tg
  ushort* s4 = (ushort*)(ws + 4 * SLOT);   // msda_out
  float*  sa = (float*)(ws + 5 * SLOT);    // [B][P][192] offs+attn
  char* wbase = ws + 5 * SLOT + SAB;
  ushort* wb  = (ushort*)wbase;            // 1472x256 bf16
  ushort* wvp = (ushort*)(wbase + (size_t)1472 * 256 * 2);   // 256x256 bf16
  float* bsa  = (float*)(wbase + (size_t)1472 * 256 * 2 + (size_t)256 * 256 * 2);
  float* bvp  = bsa + 192;

  ushort* wb_in1 = wb;
  ushort* wb_o   = wb + 65536;
  ushort* wb_t1  = wb + 131072;
  ushort* wb_t2  = wb + 196608;
  ushort* wb_out = wb + 262144;
  ushort* wb_sa  = wb + 327680;            // 192 rows: Ws then Wa

  dim3 blk(256);
  dim3 gT(PIX / 32, CH / 32, 2 * BATCH);
  dim3 gF(PIX / 128, 4, BATCH);            // Cout=256
  dim3 gS(PIX / 128, 3, BATCH);            // Cout=192
  const size_t OBS = (size_t)PIX * CH;     // pm bf16 batch stride (elems)

  wprep_k<<<1473, blk, 0, stream>>>(W_in1, Wo, Wt1, Wt2, Wout, Ws, Wa, bs_off, ba, wb, bsa);
  wvcomp_k<<<256, blk, 0, stream>>>(Wv, W_in2, b_in2, bv, wvp, bvp);
  tconv2_k<<<gT, blk, 0, stream>>>(xt, xt_1, s0, s1);

  gemm2_k<0, false, 0><<<gF, blk, 0, stream>>>(s0, nullptr, wb_in1, b_in1, s2, CH, OBS);          // x1
  gemm2_k<0, false, 0><<<gF, blk, 0, stream>>>(s1, nullptr, wvp, bvp, s3, CH, OBS);               // value
  gemm2_k<0, false, 2><<<gS, blk, 0, stream>>>(s2, nullptr, wb_sa, bsa, sa, 192, (size_t)PIX * 192); // offs+attn
  msda_k<<<dim3((BATCH * PIX * 16) / 256), blk, 0, stream>>>(s3, sa, s4);
  gemm2_k<0, false, 0><<<gF, blk, 0, stream>>>(s4, nullptr, wb_o, bo, s0, CH, OBS);               // xt_star
  gemm2_k<1, true , 0><<<gF, blk, 0, stream>>>(s0, s2, wb_t1, bt1, s1, CH, OBS);                  // h1
  gemm2_k<0, false, 0><<<gF, blk, 0, stream>>>(s1, nullptr, wb_t2, bt2, s3, CH, OBS);             // tg
  gemm2_k<2, true , 1><<<gF, blk, 0, stream>>>(s3, s2, wb_out, bout, d_out, PIX, (size_t)CH * PIX); // out
}

// Round 10
// 164.536 us; speedup vs baseline: 2.6191x; 1.0024x over previous
//
#include <hip/hip_runtime.h>
#include <math.h>

// ---------------------------------------------------------------------------
// TemporalGuidedModule round 10 = r9 +
//  - gemm2: BK=32, 24KB dbuf LDS -> 6 blocks/CU (was 3). 64B LDS rows,
//    swizzle slot = seg ^ ((row>>1)&3) (2-way aliasing = free).
//  - sa tensor bf16 pixel-major (write halved; msda decodes bf16).
// ---------------------------------------------------------------------------

#define PIX 16384
#define BATCH 2
#define CH 256

typedef short bf16x8 __attribute__((ext_vector_type(8)));
typedef float f32x4 __attribute__((ext_vector_type(4)));

typedef const __attribute__((address_space(1))) void* as1cv;
typedef __attribute__((address_space(3))) void* as3v;
__device__ __forceinline__ void gl_lds16(const void* g, void* l) {
  __builtin_amdgcn_global_load_lds((as1cv)g, (as3v)l, 16, 0, 0);
}

__device__ __forceinline__ ushort f2bf(float f) {
  union { float f; unsigned u; } v; v.f = f;
  unsigned u = v.u;
  unsigned r = u + 0x7fffu + ((u >> 16) & 1u);   // RNE
  return (ushort)(r >> 16);
}
__device__ __forceinline__ float bfl(unsigned u) {
  union { unsigned u; float f; } v; v.u = u << 16; return v.f;
}
__device__ __forceinline__ float bfh(unsigned u) {
  union { unsigned u; float f; } v; v.u = u & 0xffff0000u; return v.f;
}
__device__ __forceinline__ unsigned fuse_u32(unsigned a, unsigned b, bool mul) {
  float rl = mul ? bfl(a) * bfl(b) : bfl(a) + bfl(b);
  float rh = mul ? bfh(a) * bfh(b) : bfh(a) + bfh(b);
  return (unsigned)f2bf(rl) | ((unsigned)f2bf(rh) << 16);
}

// --------------------------------------------------------------------------
// Weight prep + bias concat.
// --------------------------------------------------------------------------
__global__ __launch_bounds__(256) void wprep_k(
    const float* __restrict__ W_in1, const float* __restrict__ Wo,
    const float* __restrict__ Wt1, const float* __restrict__ Wt2,
    const float* __restrict__ Wout, const float* __restrict__ Ws,
    const float* __restrict__ Wa, const float* __restrict__ bs_off,
    const float* __restrict__ ba, ushort* __restrict__ wb,
    float* __restrict__ bsa)
{
  const int blk = blockIdx.x, k = threadIdx.x;
  if (blk >= 1472) {
    if (k < 128) bsa[k] = bs_off[k];
    else if (k < 192) bsa[k] = ba[k - 128];
    return;
  }
  const float* src;
  if (blk < 256) src = W_in1 + (size_t)blk * 256;
  else if (blk < 512) src = Wo + (size_t)(blk - 256) * 256;
  else if (blk < 768) src = Wt1 + (size_t)(blk - 512) * 256;
  else if (blk < 1024) src = Wt2 + (size_t)(blk - 768) * 256;
  else if (blk < 1280) src = Wout + (size_t)(blk - 1024) * 256;
  else if (blk < 1408) src = Ws + (size_t)(blk - 1280) * 256;
  else src = Wa + (size_t)(blk - 1408) * 256;
  wb[(size_t)blk * 256 + k] = f2bf(src[k]);
}

// Wv' = Wv @ W_in2 (bf16), bv' = Wv @ b_in2 + bv.
__global__ __launch_bounds__(256) void wvcomp_k(
    const float* __restrict__ Wv, const float* __restrict__ W_in2,
    const float* __restrict__ b_in2, const float* __restrict__ bv,
    ushort* __restrict__ Wvp, float* __restrict__ bvp)
{
  const int o = blockIdx.x, k = threadIdx.x;
  float acc = 0.f;
  #pragma unroll 8
  for (int c = 0; c < 256; ++c)
    acc += Wv[(size_t)o * 256 + c] * W_in2[(size_t)c * 256 + k];
  Wvp[(size_t)o * 256 + k] = f2bf(acc);
  __shared__ float red[256];
  red[k] = Wv[(size_t)o * 256 + k] * b_in2[k];
  __syncthreads();
  for (int s = 128; s > 0; s >>= 1) {
    if (k < s) red[k] += red[k + s];
    __syncthreads();
  }
  if (k == 0) bvp[o] = red[0] + bv[o];
}

// --------------------------------------------------------------------------
// Transpose-convert x2: z = (input<<1)|batch. [B][C][P] f32 -> [B][P][C] bf16.
// --------------------------------------------------------------------------
__global__ __launch_bounds__(256) void tconv2_k(
    const float* __restrict__ inA, const float* __restrict__ inB,
    ushort* __restrict__ outA, ushort* __restrict__ outB)
{
  __shared__ float t[32][33];
  const int tid = threadIdx.x;
  const int z = blockIdx.z;
  const int b = z & 1;
  const float* in = (z < 2) ? inA : inB;
  ushort* out = (z < 2) ? outA : outB;
  const int p0 = blockIdx.x * 32, c0 = blockIdx.y * 32;
  const int tx = tid & 31, ty = tid >> 5;
  const float* inb = in + (size_t)b * CH * PIX;
  #pragma unroll
  for (int i = 0; i < 4; ++i)
    t[ty + i * 8][tx] = inb[(size_t)(c0 + ty + i * 8) * PIX + p0 + tx];
  __syncthreads();
  const int cx = (tid & 15) * 2, py = tid >> 4;
  ushort* outb = out + (size_t)b * PIX * CH;
  #pragma unroll
  for (int i = 0; i < 2; ++i) {
    int pl = py + i * 16;
    unsigned lo = f2bf(t[cx][pl]);
    unsigned hi = f2bf(t[cx + 1][pl]);
    *(unsigned*)(outb + (size_t)(p0 + pl) * CH + c0 + cx) = lo | (hi << 16);
  }
}

// --------------------------------------------------------------------------
// MFMA GEMM: 128p x 64o tile, BK=32, 8 K-steps, 4 waves.
// LDS: X dbuf 2x8KB [128 rows][64B] + W dbuf 2x4KB [64 rows][64B] = 24KB.
// Swizzle: 16B chunk seg of row r at slot seg ^ ((r>>1)&3).
// FUSE=0: gl_lds staging, dest lane-linear, source pre-swizzled.
// FUSE!=0: register staging with fused elementwise.
// OMODE 0: pm bf16 out (ldo param); 1: cm f32 out (transposed bounce, 33.8KB).
// --------------------------------------------------------------------------
template<int FUSE, bool RELU, int OMODE>
__global__ __launch_bounds__(256, 4) void gemm2_k(
    const ushort* __restrict__ in, const ushort* __restrict__ in2,
    const ushort* __restrict__ Wb, const float* __restrict__ bias,
    void* __restrict__ out, int ldo, size_t obstride)
{
  constexpr int SMEMSZ = (OMODE == 0) ? 24576 : 34816;
  __shared__ __align__(16) char smem[SMEMSZ];
  const int tid = threadIdx.x;
  const int b = blockIdx.z;
  const int p0 = blockIdx.x * 128;
  const int o0 = blockIdx.y * 64;

  const ushort* inb = in + (size_t)b * PIX * CH;

  const int srow = tid >> 2;            // X rows 0..63 (+64), W rows 0..63
  const int sseg = tid & 3;             // 16B chunk within 64B row
  const int swz0 = (srow >> 1) & 3;     // row swizzle key (row < 64)
  const int swz1 = ((srow + 64) >> 1) & 3;
  // FUSE=0: pre-swizzled global source; FUSE!=0: linear source.
  const int gseg0 = (FUSE == 0) ? (sseg ^ swz0) : sseg;
  const int gseg1 = (FUSE == 0) ? (sseg ^ swz1) : sseg;
  const ushort* xsrc0 = inb + (size_t)(p0 + srow) * CH + gseg0 * 8;
  const ushort* xsrc1 = inb + (size_t)(p0 + srow + 64) * CH + gseg1 * 8;
  const ushort* x2src0 = (FUSE != 0)
      ? in2 + (size_t)b * PIX * CH + (size_t)(p0 + srow) * CH + sseg * 8 : (const ushort*)nullptr;
  const ushort* x2src1 = (FUSE != 0)
      ? in2 + (size_t)b * PIX * CH + (size_t)(p0 + srow + 64) * CH + sseg * 8 : (const ushort*)nullptr;
  const ushort* wsrc = Wb + (size_t)(o0 + srow) * CH + gseg0 * 8;

  const int l = tid & 63, wv = tid >> 6;
  const int lr = l & 15, g4 = l >> 4;

  f32x4 acc[2][4];
  #pragma unroll
  for (int i = 0; i < 2; ++i)
    #pragma unroll
    for (int j = 0; j < 4; ++j) acc[i][j] = (f32x4){0.f, 0.f, 0.f, 0.f};

  uint4 xr[2], x2r[2], wr;

// ---- FUSE=0: async DMA staging (X 2 chunks + W 1 chunk per thread) ----
#define STAGE_GLL(buf, kb)                                                     \
  {                                                                            \
    gl_lds16(xsrc0 + (kb), smem + (buf) * 8192 + tid * 16);                    \
    gl_lds16(xsrc1 + (kb), smem + (buf) * 8192 + 4096 + tid * 16);             \
    gl_lds16(wsrc + (kb), smem + 16384 + (buf) * 4096 + tid * 16);             \
  }

// ---- FUSE!=0: register staging ----
#define LOADT(kb)                                                              \
  {                                                                            \
    xr[0] = *(const uint4*)(x2src0 ? xsrc0 + (kb) : xsrc0 + (kb));             \
    xr[1] = *(const uint4*)(xsrc1 + (kb));                                     \
    x2r[0] = *(const uint4*)(x2src0 + (kb));                                   \
    x2r[1] = *(const uint4*)(x2src1 + (kb));                                   \
    wr = *(const uint4*)(wsrc + (kb));                                         \
  }

#define WRITET(buf)                                                            \
  {                                                                            \
    _Pragma("unroll")                                                          \
    for (int r = 0; r < 2; ++r) {                                              \
      uint4 v = xr[r];                                                         \
      unsigned* pa = (unsigned*)&v;                                            \
      const unsigned* pb = (const unsigned*)&x2r[r];                           \
      _Pragma("unroll")                                                        \
      for (int w = 0; w < 4; ++w) pa[w] = fuse_u32(pa[w], pb[w], FUSE == 1);   \
      const int sw = r ? swz1 : swz0;                                          \
      *(uint4*)(smem + (buf) * 8192 + r * 4096 + srow * 64 +                   \
                ((sseg ^ sw) * 16)) = v;                                       \
    }                                                                          \
    *(uint4*)(smem + 16384 + (buf) * 4096 + srow * 64 +                        \
              ((sseg ^ swz0) * 16)) = wr;                                      \
  }

  if (FUSE == 0) { STAGE_GLL(0, 0) }
  else           { LOADT(0) WRITET(0) }
  __syncthreads();

  for (int t = 0; t < 8; ++t) {
    if (t < 7) {
      if (FUSE == 0) { STAGE_GLL((t + 1) & 1, (t + 1) * 32) }
      else           { LOADT((t + 1) * 32) }
    }
    const char* XB = smem + (t & 1) * 8192;
    const char* WB = smem + 16384 + (t & 1) * 4096;
    bf16x8 af[2], bfr[4];
    #pragma unroll
    for (int fm = 0; fm < 2; ++fm) {
      const int p = wv * 32 + fm * 16 + lr;
      af[fm] = *(const bf16x8*)(XB + p * 64 + ((g4 ^ ((p >> 1) & 3)) * 16));
    }
    #pragma unroll
    for (int fn = 0; fn < 4; ++fn) {
      const int o = fn * 16 + lr;
      bfr[fn] = *(const bf16x8*)(WB + o * 64 + ((g4 ^ ((o >> 1) & 3)) * 16));
    }
    #pragma unroll
    for (int fm = 0; fm < 2; ++fm)
      #pragma unroll
      for (int fn = 0; fn < 4; ++fn)
        acc[fm][fn] = __builtin_amdgcn_mfma_f32_16x16x32_bf16(af[fm], bfr[fn], acc[fm][fn], 0, 0, 0);
    if (t < 7 && FUSE != 0) { WRITET((t + 1) & 1) }
    __syncthreads();
  }
#undef STAGE_GLL
#undef LOADT
#undef WRITET

  // ---- epilogue ---- C/D: col(o) = lr, row(p) = g4*4 + reg
  float bvv[4];
  #pragma unroll
  for (int fn = 0; fn < 4; ++fn) bvv[fn] = bias[o0 + fn * 16 + lr];

  if (OMODE == 1) {               // cm f32 via TRANSPOSED bounce El2[64][132] f32
    float* El2 = (float*)smem;
    #pragma unroll
    for (int fm = 0; fm < 2; ++fm)
      #pragma unroll
      for (int fn = 0; fn < 4; ++fn) {
        float4 v;
        v.x = acc[fm][fn][0] + bvv[fn]; v.y = acc[fm][fn][1] + bvv[fn];
        v.z = acc[fm][fn][2] + bvv[fn]; v.w = acc[fm][fn][3] + bvv[fn];
        if (RELU) {
          v.x = fmaxf(v.x, 0.f); v.y = fmaxf(v.y, 0.f);
          v.z = fmaxf(v.z, 0.f); v.w = fmaxf(v.w, 0.f);
        }
        *(float4*)&El2[(size_t)(fn * 16 + lr) * 132 + wv * 32 + fm * 16 + g4 * 4] = v;
      }
    __syncthreads();
    float* outb = (float*)out + (size_t)b * obstride;
    const int og = tid >> 5, seg = tid & 31;
    #pragma unroll
    for (int r = 0; r < 8; ++r) {
      const int orow = og + r * 8;
      float4 v = *(float4*)(smem + orow * 528 + seg * 16);
      *(float4*)(outb + (size_t)(o0 + orow) * ldo + p0 + seg * 4) = v;
    }
  } else {                        // pm bf16 via LDS bounce [128][72] halves
    ushort* El = (ushort*)smem;
    #pragma unroll
    for (int fm = 0; fm < 2; ++fm)
      #pragma unroll
      for (int fn = 0; fn < 4; ++fn)
        #pragma unroll
        for (int r = 0; r < 4; ++r) {
          const int p = wv * 32 + fm * 16 + g4 * 4 + r;
          float v = acc[fm][fn][r] + bvv[fn];
          if (RELU) v = fmaxf(v, 0.f);
          El[p * 72 + fn * 16 + lr] = f2bf(v);
        }
    __syncthreads();
    ushort* outb = (ushort*)out + (size_t)b * obstride;
    const int rg = tid >> 3, seg = tid & 7;
    #pragma unroll
    for (int r = 0; r < 4; ++r) {
      const int row = rg + r * 32;
      uint4 v = *(uint4*)(smem + row * 144 + seg * 16);
      *(uint4*)(outb + (size_t)(p0 + row) * ldo + o0 + seg * 8) = v;
    }
  }
}

// --------------------------------------------------------------------------
// Fused MSDA — r8 structure; sa now PM BF16 [B][P][192] (decode in-register).
// value pm bf16 [B][P][256]; out pm bf16.
// --------------------------------------------------------------------------
__global__ __launch_bounds__(256) void msda_k(
    const ushort* __restrict__ value, const ushort* __restrict__ sa,
    ushort* __restrict__ out)
{
  const int t = blockIdx.x * 256 + threadIdx.x;   // B*P*16
  const int dh = t & 1;
  const int h = (t >> 1) & 7;
  const int pg = t >> 4;
  const int b = pg >> 14;
  const int p = pg & (PIX - 1);
  const int px = p & 127, py = p >> 7;

  const ushort* vb = value + (size_t)b * PIX * CH;
  const ushort* sp = sa + (size_t)pg * 192;

  // logits: 8 bf16 = one uint4
  uint4 lgv = *(const uint4*)(sp + 128 + h * 8);
  const unsigned* lgw = (const unsigned*)&lgv;
  float lg[8];
  #pragma unroll
  for (int i = 0; i < 4; ++i) { lg[2 * i] = bfl(lgw[i]); lg[2 * i + 1] = bfh(lgw[i]); }
  float m = lg[0];
  #pragma unroll
  for (int i = 1; i < 8; ++i) m = fmaxf(m, lg[i]);
  float s = 0.f;
  #pragma unroll
  for (int i = 0; i < 8; ++i) { lg[i] = __expf(lg[i] - m); s += lg[i]; }
  const float inv = 1.f / s;

  // offsets: 16 bf16 = two uint4
  uint4 ov0 = *(const uint4*)(sp + h * 16);
  uint4 ov1 = *(const uint4*)(sp + h * 16 + 8);
  float of[16];
  {
    const unsigned* ow = (const unsigned*)&ov0;
    #pragma unroll
    for (int i = 0; i < 4; ++i) { of[2 * i] = bfl(ow[i]); of[2 * i + 1] = bfh(ow[i]); }
    const unsigned* ow1 = (const unsigned*)&ov1;
    #pragma unroll
    for (int i = 0; i < 4; ++i) { of[8 + 2 * i] = bfl(ow1[i]); of[8 + 2 * i + 1] = bfh(ow1[i]); }
  }

  float acc[16];
  #pragma unroll
  for (int i = 0; i < 16; ++i) acc[i] = 0.f;

  #pragma unroll
  for (int pt = 0; pt < 8; ++pt) {
    const float ox = of[2 * pt], oy = of[2 * pt + 1];
    const float aw = lg[pt] * inv;
    const float ix = px + ox, iy = py + oy;   // grid_sample -0.5 cancels
    const float xf = floorf(ix), yf = floorf(iy);
    const float fx = ix - xf, fy = iy - yf;
    const int x0 = (int)xf, y0 = (int)yf;
    #pragma unroll
    for (int cr = 0; cr < 4; ++cr) {
      const int dx = cr & 1, dy = cr >> 1;
      const int xx = x0 + dx, yy = y0 + dy;
      const float wx = dx ? fx : (1.f - fx);
      const float wy = dy ? fy : (1.f - fy);
      const bool valid = ((unsigned)xx < 128u) & ((unsigned)yy < 128u);
      float w = valid ? (wx * wy * aw) : 0.f;
      const int xc = min(max(xx, 0), 127), yc = min(max(yy, 0), 127);
      const ushort* vr = vb + ((size_t)(yc * 128 + xc) * CH + h * 32 + dh * 16);
      uint4 q0 = *(const uint4*)vr;
      uint4 q1 = *(const uint4*)(vr + 8);
      const unsigned* qw0 = (const unsigned*)&q0;
      const unsigned* qw1 = (const unsigned*)&q1;
      #pragma unroll
      for (int ww = 0; ww < 4; ++ww) {
        acc[2 * ww + 0] = fmaf(w, bfl(qw0[ww]), acc[2 * ww + 0]);
        acc[2 * ww + 1] = fmaf(w, bfh(qw0[ww]), acc[2 * ww + 1]);
        acc[8 + 2 * ww + 0] = fmaf(w, bfl(qw1[ww]), acc[8 + 2 * ww + 0]);
        acc[8 + 2 * ww + 1] = fmaf(w, bfh(qw1[ww]), acc[8 + 2 * ww + 1]);
      }
    }
  }
  unsigned r[8];
  #pragma unroll
  for (int k = 0; k < 8; ++k)
    r[k] = (unsigned)f2bf(acc[2 * k]) | ((unsigned)f2bf(acc[2 * k + 1]) << 16);
  ushort* dst = out + (size_t)pg * CH + h * 32 + dh * 16;
  *(uint4*)dst = *(uint4*)&r[0];
  *(uint4*)(dst + 8) = *(uint4*)&r[4];
}

extern "C" void kernel_launch(void* const* d_in, const int* in_sizes, int n_in,
                              void* d_out, int out_size, void* d_ws, size_t ws_size,
                              hipStream_t stream)
{
  const float* xt     = (const float*)d_in[0];
  const float* xt_1   = (const float*)d_in[1];
  const float* W_in1  = (const float*)d_in[2];
  const float* b_in1  = (const float*)d_in[3];
  const float* W_in2  = (const float*)d_in[4];
  const float* b_in2  = (const float*)d_in[5];
  const float* Wv     = (const float*)d_in[6];
  const float* bv     = (const float*)d_in[7];
  const float* Ws     = (const float*)d_in[8];
  const float* bs_off = (const float*)d_in[9];
  const float* Wa     = (const float*)d_in[10];
  const float* ba     = (const float*)d_in[11];
  const float* Wo     = (const float*)d_in[12];
  const float* bo     = (const float*)d_in[13];
  const float* Wt1    = (const float*)d_in[14];
  const float* bt1    = (const float*)d_in[15];
  const float* Wt2    = (const float*)d_in[16];
  const float* bt2    = (const float*)d_in[17];
  const float* Wout   = (const float*)d_in[18];
  const float* bout   = (const float*)d_in[19];

  char* ws = (char*)d_ws;
  const size_t SLOT = (size_t)BATCH * PIX * CH * 2;          // 16.78 MB
  const size_t SAB  = (size_t)BATCH * PIX * 192 * 2;         // 12.6 MB (bf16)
  ushort* s0 = (ushort*)(ws + 0 * SLOT);   // xt_pm  -> xt_star
  ushort* s1 = (ushort*)(ws + 1 * SLOT);   // xt1_pm -> h1
  ushort* s2 = (ushort*)(ws + 2 * SLOT);   // x1 (live to end)
  ushort* s3 = (ushort*)(ws + 3 * SLOT);   // value  -> tg
  ushort* s4 = (ushort*)(ws + 4 * SLOT);   // msda_out
  ushort* sa = (ushort*)(ws + 5 * SLOT);   // [B][P][192] offs+attn (bf16)
  char* wbase = ws + 5 * SLOT + SAB;
  ushort* wb  = (ushort*)wbase;            // 1472x256 bf16
  ushort* wvp = (ushort*)(wbase + (size_t)1472 * 256 * 2);   // 256x256 bf16
  float* bsa  = (float*)(wbase + (size_t)1472 * 256 * 2 + (size_t)256 * 256 * 2);
  float* bvp  = bsa + 192;

  ushort* wb_in1 = wb;
  ushort* wb_o   = wb + 65536;
  ushort* wb_t1  = wb + 131072;
  ushort* wb_t2  = wb + 196608;
  ushort* wb_out = wb + 262144;
  ushort* wb_sa  = wb + 327680;            // 192 rows: Ws then Wa

  dim3 blk(256);
  dim3 gT(PIX / 32, CH / 32, 2 * BATCH);
  dim3 gF(PIX / 128, 4, BATCH);            // Cout=256
  dim3 gS(PIX / 128, 3, BATCH);            // Cout=192
  const size_t OBS = (size_t)PIX * CH;     // pm bf16 batch stride (elems)

  wprep_k<<<1473, blk, 0, stream>>>(W_in1, Wo, Wt1, Wt2, Wout, Ws, Wa, bs_off, ba, wb, bsa);
  wvcomp_k<<<256, blk, 0, stream>>>(Wv, W_in2, b_in2, bv, wvp, bvp);
  tconv2_k<<<gT, blk, 0, stream>>>(xt, xt_1, s0, s1);

  gemm2_k<0, false, 0><<<gF, blk, 0, stream>>>(s0, nullptr, wb_in1, b_in1, s2, CH, OBS);          // x1
  gemm2_k<0, false, 0><<<gF, blk, 0, stream>>>(s1, nullptr, wvp, bvp, s3, CH, OBS);               // value
  gemm2_k<0, false, 0><<<gS, blk, 0, stream>>>(s2, nullptr, wb_sa, bsa, sa, 192, (size_t)PIX * 192); // offs+attn (bf16)
  msda_k<<<dim3((BATCH * PIX * 16) / 256), blk, 0, stream>>>(s3, sa, s4);
  gemm2_k<0, false, 0><<<gF, blk, 0, stream>>>(s4, nullptr, wb_o, bo, s0, CH, OBS);               // xt_star
  gemm2_k<1, true , 0><<<gF, blk, 0, stream>>>(s0, s2, wb_t1, bt1, s1, CH, OBS);                  // h1
  gemm2_k<0, false, 0><<<gF, blk, 0, stream>>>(s1, nullptr, wb_t2, bt2, s3, CH, OBS);             // tg
  gemm2_k<2, true , 1><<<gF, blk, 0, stream>>>(s3, s2, wb_out, bout, d_out, PIX, (size_t)CH * PIX); // out
}